// Round 14
// baseline (1679.833 us; speedup 1.0000x reference)
//
#include <hip/hip_runtime.h>
#include <math.h>

#define HH 128
#define NPIX 16384
#define BB 8
#define MM 4096
#define NN 16384
#define LRELU_S 0.1f

typedef __attribute__((ext_vector_type(8))) short bf16x8;
typedef __attribute__((ext_vector_type(4))) float f32x4;

__device__ __forceinline__ float leaky_(float v){ return v >= 0.f ? v : LRELU_S*v; }
__device__ __forceinline__ float clamp01(float v){ return fminf(fmaxf(v, 0.f), 1.f); }
__device__ __forceinline__ float clamp02(float v){ return fminf(fmaxf(v, 0.f), 2.f); }
__device__ __forceinline__ unsigned short f2bf(float f){
  unsigned u = __float_as_uint(f);
  u = (u + 0x7FFFu + ((u >> 16) & 1u)) >> 16;
  return (unsigned short)u;
}
__device__ __forceinline__ float bf2f(unsigned short s){
  return __uint_as_float(((unsigned)s) << 16);
}

// ---------- prep_pack (R11/R13-proven): A f32 -> Apk[((mt*2048+k8)*16+col)*8+e] ----------
__global__ __launch_bounds__(256) void k_prep_pack(const float* __restrict__ A_,
                                                   unsigned short* __restrict__ Apk){
  __shared__ unsigned short lb[16][1032];
  int blk = blockIdx.x;                  // 4096 = mt(256) x ch(16)
  int mt = blk >> 4, ch = blk & 15;
  int t = threadIdx.x;
  #pragma unroll
  for (int i=0;i<16;++i){
    float4 v = *(const float4*)&A_[(size_t)(mt*16+i)*NN + ch*1024 + t*4];
    unsigned short o[4] = {f2bf(v.x),f2bf(v.y),f2bf(v.z),f2bf(v.w)};
    *(uint2*)&lb[i][t*4] = *(uint2*)o;
  }
  __syncthreads();
  size_t base = ((size_t)mt*2048 + ch*128)*128;
  #pragma unroll
  for (int j=0;j<8;++j){
    int o = j*256 + t;
    int k8l = o >> 4, col = o & 15;
    uint4 v = *(const uint4*)&lb[col][k8l*8];
    *(uint4*)&Apk[base + (size_t)o*8] = v;
  }
}

// ---------- dn[b] = ||d[b,:]|| ----------
__global__ __launch_bounds__(256) void k_dn(const float* __restrict__ d, float* __restrict__ dn){
  int b = blockIdx.x, t = threadIdx.x;
  float ss = 0.f;
  for (int m=t; m<MM; m+=256){ float v = d[b*MM + m]; ss += v*v; }
  #pragma unroll
  for (int off=32; off; off>>=1) ss += __shfl_down(ss, off);
  __shared__ float red[4];
  if ((t & 63) == 0) red[t>>6] = ss;
  __syncthreads();
  if (t == 0) dn[b] = sqrtf(red[0]+red[1]+red[2]+red[3]);
}

// conv LDS (bf16) index helpers (R10-proven)
#define XS(i,j)   xsB[(i)*128+(j)]
#define BA(c,i,j) bufAB[((c)*22+(i))*128+(j)]
#define BBD(c,i,j) bufBB[((c)*18+(i))*128+(j)]

// ---------- K1: het grid 1152. blocks 0..1023 gemm1p (R13); 1024..1151 conv (R10 bf16) ----------
__global__ __launch_bounds__(256) void k_g1c(const unsigned short* __restrict__ Apk,
    const unsigned short* __restrict__ xtt, const float* __restrict__ x,
    const float* __restrict__ wK, const float* __restrict__ w1, const float* __restrict__ b1,
    const float* __restrict__ w2, const float* __restrict__ b2,
    const float* __restrict__ w3, const float* __restrict__ b3,
    const float* __restrict__ alpha,
    float* __restrict__ e_part, float* __restrict__ rk1){
  __shared__ float smem[6656];           // 26624 B: conv bf16 bufs / gemm1 part(4KB)
  __shared__ float wKs[18], w1s[100], w2s[100], w3s[100], bs[6];
  int blk = blockIdx.x, t = threadIdx.x;

  if (blk < 1024){
    // ===== gemm1p (R13-proven verbatim) =====
    float* part = smem;                  // [4][16][16]
    int mt = blk >> 2, ng = blk & 3;
    int w = t >> 6, lane = t & 63;
    int kg = lane >> 4, col = lane & 15;
    const unsigned short* Ap = Apk + (((size_t)mt*2048 + ng*512 + w*128 + kg)*16 + col)*8;
    const unsigned short* Bp = xtt + ((size_t)(ng*512 + w*128 + kg)*16 + col)*8;
    f32x4 acc = {0.f,0.f,0.f,0.f};
    #pragma unroll 8
    for (int s=0; s<32; ++s){
      bf16x8 a = *(const bf16x8*)(Ap + s*512);
      bf16x8 b = *(const bf16x8*)(Bp + s*512);
      acc = __builtin_amdgcn_mfma_f32_16x16x32_bf16(a, b, acc, 0, 0, 0);
    }
    #pragma unroll
    for (int j=0;j<4;++j) part[w*256 + (kg*4+j)*16 + col] = acc[j];
    __syncthreads();
    int r = t >> 4, b = t & 15;
    float s = part[r*16+b] + part[256+r*16+b] + part[512+r*16+b] + part[768+r*16+b];
    e_part[((size_t)ng*MM + mt*16 + r)*16 + b] = s;
    return;
  }

  // ===== conv role (R10-proven bf16-LDS slab-8) =====
  unsigned short* xsB   = (unsigned short*)&smem[0];     // [24][128]
  unsigned short* bufAB = (unsigned short*)&smem[1536];  // [2][22][128]
  unsigned short* bufBB = (unsigned short*)&smem[4352];  // [2][18][128]
  int cb = blk - 1024;
  int b = cb >> 4, slab = cb & 15, r0 = slab*8;
  float twoa = 2.f*clamp02(alpha[0]);
  for (int i=t;i<18;i+=256) wKs[i]=wK[i];
  for (int i=t;i<100;i+=256){ w1s[i]=w1[i]; w2s[i]=w2[i]; w3s[i]=w3[i]; }
  if (t<2){ bs[t]=b1[t]; bs[2+t]=b2[t]; bs[4+t]=b3[t]; }
  for (int idx=t; idx<24*128; idx+=256){
    int i = idx>>7, j = idx&127, ir = r0-8+i;
    XS(i,j) = f2bf(((unsigned)ir < 128u) ? x[b*NPIX + ir*HH + j] : 0.f);
  }
  __syncthreads();
  for (int c=0;c<2;++c)
    for (int idx=t; idx<22*128; idx+=256){
      int i = idx>>7, j = idx&127, ir = r0-7+i;
      float s = 0.f;
      if ((unsigned)ir < 128u){
        #pragma unroll
        for (int di=0;di<3;++di)
          #pragma unroll
          for (int dj=0;dj<3;++dj){
            int jj = j+dj-1;
            if ((unsigned)jj < 128u) s += bf2f(XS(i+di,jj))*wKs[(c*3+di)*3+dj];
          }
      }
      BA(c,i,j) = f2bf(s);
    }
  __syncthreads();
  for (int o=0;o<2;++o)
    for (int idx=t; idx<18*128; idx+=256){
      int i = idx>>7, j = idx&127, ir = r0-5+i;
      float v = 0.f;
      if ((unsigned)ir < 128u){
        float s = bs[o];
        #pragma unroll
        for (int c=0;c<2;++c)
          #pragma unroll
          for (int di=0;di<5;++di)
            #pragma unroll
            for (int dj=0;dj<5;++dj){
              int jj = j+dj-2;
              if ((unsigned)jj < 128u) s += bf2f(BA(c,i+di,jj))*w1s[(o*2+c)*25+di*5+dj];
            }
        v = bf2f(BA(o,i+2,j)) + leaky_(s);
      }
      BBD(o,i,j) = f2bf(v);
    }
  __syncthreads();
  for (int o=0;o<2;++o)
    for (int idx=t; idx<14*128; idx+=256){
      int i = idx>>7, j = idx&127, ir = r0-3+i;
      float v = 0.f;
      if ((unsigned)ir < 128u){
        float s = bs[2+o];
        #pragma unroll
        for (int c=0;c<2;++c)
          #pragma unroll
          for (int di=0;di<5;++di)
            #pragma unroll
            for (int dj=0;dj<5;++dj){
              int jj = j+dj-2;
              if ((unsigned)jj < 128u) s += bf2f(BBD(c,i+di,jj))*w2s[(o*2+c)*25+di*5+dj];
            }
        v = bf2f(BBD(o,i+2,j)) + leaky_(s);
      }
      BA(o,i,j) = f2bf(v);
    }
  __syncthreads();
  for (int o=0;o<2;++o)
    for (int idx=t; idx<10*128; idx+=256){
      int i = idx>>7, j = idx&127, ir = r0-1+i;
      float v = 0.f;
      if ((unsigned)ir < 128u){
        float s = bs[4+o];
        #pragma unroll
        for (int c=0;c<2;++c)
          #pragma unroll
          for (int di=0;di<5;++di)
            #pragma unroll
            for (int dj=0;dj<5;++dj){
              int jj = j+dj-2;
              if ((unsigned)jj < 128u) s += bf2f(BA(c,i+di,jj))*w3s[(o*2+c)*25+di*5+dj];
            }
        v = bf2f(BA(o,i+2,j)) + leaky_(s);
      }
      BBD(o,i,j) = f2bf(v);
    }
  __syncthreads();
  for (int c=0;c<2;++c)
    for (int idx=t; idx<10*128; idx+=256){
      int i = idx>>7, j = idx&127, ir = r0-1+i;
      float v = 0.f;
      if ((unsigned)ir < 128u){
        float kx = 0.f;
        #pragma unroll
        for (int di=0;di<3;++di)
          #pragma unroll
          for (int dj=0;dj<3;++dj){
            int jj = j+dj-1;
            if ((unsigned)jj < 128u) kx += bf2f(XS(i+6+di,jj))*wKs[(c*3+di)*3+dj];
          }
        v = twoa*(kx - bf2f(BBD(c,i,j)));
      }
      BA(c,i,j) = f2bf(v);
    }
  __syncthreads();
  for (int idx=t; idx<8*128; idx+=256){
    int i = idx>>7, j = idx&127, ir = r0+i;
    float s = 0.f;
    #pragma unroll
    for (int c=0;c<2;++c)
      #pragma unroll
      for (int di=0;di<3;++di)
        #pragma unroll
        for (int dj=0;dj<3;++dj){
          int jj = j+dj-1;
          if ((unsigned)jj < 128u) s += bf2f(BA(c,i+di,jj))*wKs[(c*3+(2-di))*3+(2-dj)];
        }
    rk1[b*NPIX + ir*HH + j] = s;
  }
}

// ---------- K2: gemm2b — uint4 loads, 4-deep batch, butterfly reduce. 1024 blocks ----------
// Block (msp 0..7, nb 0..127): m in [msp*512,+512), k8 in [nb*16,+16).
// Thread: col=t&15 (m within mt), k8l=t>>4 (0..15). acc[8b][8e].
__global__ __launch_bounds__(256) void k_gemm2b(const unsigned short* __restrict__ Apk,
    const float* __restrict__ e_part, const float* __restrict__ d_,
    float* __restrict__ up, float* __restrict__ d2p){
  __shared__ float zs[8][512];
  __shared__ float red8s[64];
  int blk = blockIdx.x;
  int msp = blk >> 7, nb = blk & 127;
  int m0 = msp*512, mt0 = msp*32, k80 = nb*16;
  int t = threadIdx.x;
  for (int i=t; i<4096; i+=256){
    int ml = i >> 3, b = i & 7;
    int m = m0 + ml;
    float s = e_part[(size_t)(0*MM + m)*16 + b]
            + e_part[(size_t)(1*MM + m)*16 + b]
            + e_part[(size_t)(2*MM + m)*16 + b]
            + e_part[(size_t)(3*MM + m)*16 + b];
    zs[b][ml] = s - d_[b*MM + m];
  }
  __syncthreads();
  if (nb == 0){
    if (t < 64){
      int b = t & 7, g = t >> 3;
      float s = 0.f;
      #pragma unroll
      for (int i=0;i<64;++i){ float v = zs[b][g*64+i]; s += v*v; }
      red8s[g*8 + b] = s;
    }
    __syncthreads();
    if (t < 8){
      float s2 = 0.f;
      #pragma unroll
      for (int g=0;g<8;++g) s2 += red8s[g*8 + t];
      d2p[msp*8 + t] = s2;
    }
  }
  int col = t & 15, k8l = t >> 4;
  int k8 = k80 + k8l;
  const unsigned short* Ap = Apk + (((size_t)mt0*2048 + k8)*16 + col)*8;
  float acc[8][8];                       // [b][e]
  #pragma unroll
  for (int b=0;b<8;++b)
    #pragma unroll
    for (int e=0;e<8;++e) acc[b][e] = 0.f;
  for (int mb=0; mb<32; mb+=4){
    uint4 a4[4];
    #pragma unroll
    for (int u=0;u<4;++u)
      a4[u] = *(const uint4*)(Ap + (size_t)(mb+u)*262144);  // 2048*16*8 shorts per mt
    #pragma unroll
    for (int u=0;u<4;++u){
      float av[8];
      av[0]=bf2f((unsigned short)(a4[u].x & 0xffff)); av[1]=bf2f((unsigned short)(a4[u].x >> 16));
      av[2]=bf2f((unsigned short)(a4[u].y & 0xffff)); av[3]=bf2f((unsigned short)(a4[u].y >> 16));
      av[4]=bf2f((unsigned short)(a4[u].z & 0xffff)); av[5]=bf2f((unsigned short)(a4[u].z >> 16));
      av[6]=bf2f((unsigned short)(a4[u].w & 0xffff)); av[7]=bf2f((unsigned short)(a4[u].w >> 16));
      int ml = (mb+u)*16 + col;
      #pragma unroll
      for (int b=0;b<8;++b){
        float z = zs[b][ml];
        #pragma unroll
        for (int e=0;e<8;++e) acc[b][e] += av[e]*z;
      }
    }
  }
  #pragma unroll
  for (int mask=1; mask<16; mask<<=1)
    #pragma unroll
    for (int b=0;b<8;++b)
      #pragma unroll
      for (int e=0;e<8;++e) acc[b][e] += __shfl_xor(acc[b][e], mask);
  if (col < 8){
    int b = col;
    float4 v0 = {acc[b][0], acc[b][1], acc[b][2], acc[b][3]};
    float4 v1 = {acc[b][4], acc[b][5], acc[b][6], acc[b][7]};
    float* dst = &up[((size_t)msp*8 + b)*NN + k8*8];
    *(float4*)dst = v0;
    *(float4*)(dst+4) = v1;
  }
}

// ---------- K3: combine (R13-proven). 512 blocks ----------
__global__ __launch_bounds__(256) void k_combine3(const float* __restrict__ up,
    const float* __restrict__ rk1, const float* __restrict__ d2p,
    const float* __restrict__ dn, const float* __restrict__ delta,
    const float* __restrict__ alpha, const float* __restrict__ beta,
    float* __restrict__ x, unsigned short* __restrict__ xtt){
  __shared__ float cf_s[8];
  int t = threadIdx.x;
  if (t < 8){
    float s2 = 0.f;
    #pragma unroll
    for (int ms=0; ms<8; ++ms) s2 += d2p[ms*8 + t];
    float dist = fmaxf(sqrtf(s2), 1e-10f);
    float de = expf(delta[0]);
    float a = clamp02(alpha[0]);
    cf_s[t] = 2.f*a*(1.f - fminf(1.f, de*dn[t]/dist));
  }
  __syncthreads();
  float bta = clamp02(beta[0]);
  int o = blockIdx.x*256 + t;
  int b = o >> 14, pix = o & 16383;
  float s = 0.f;
  #pragma unroll
  for (int p=0; p<8; ++p)
    s += up[((size_t)p*8 + b)*NN + pix];
  float tot = rk1[b*NPIX + pix] + cf_s[b]*s;
  float xn = clamp01(x[b*NPIX + pix] - bta*tot);
  x[b*NPIX + pix] = xn;
  xtt[((size_t)(pix>>3)*16 + b)*8 + (pix&7)] = f2bf(xn);
}

extern "C" void kernel_launch(void* const* d_in, const int* in_sizes, int n_in,
                              void* d_out, int out_size, void* d_ws, size_t ws_size,
                              hipStream_t stream) {
  const float* d_d   = (const float*)d_in[0];
  const float* d_A   = (const float*)d_in[1];
  const float* w1    = (const float*)d_in[2];
  const float* b1    = (const float*)d_in[3];
  const float* w2    = (const float*)d_in[4];
  const float* b2    = (const float*)d_in[5];
  const float* w3    = (const float*)d_in[6];
  const float* b3    = (const float*)d_in[7];
  const float* wK    = (const float*)d_in[8];
  const float* delta = (const float*)d_in[9];
  const float* alpha = (const float*)d_in[10];
  const float* beta  = (const float*)d_in[12];

  char* p = (char*)d_ws;
  unsigned short* Apk = (unsigned short*)p; p += (size_t)MM*NN*2;      // 128 MiB (single A copy)
  unsigned short* xtt = (unsigned short*)p; p += (size_t)2048*16*8*2;  // 512 KiB
  float* x      = (float*)p; p += (size_t)BB*NPIX*4;
  float* rk1    = (float*)p; p += (size_t)BB*NPIX*4;
  float* e_part = (float*)p; p += (size_t)4*MM*16*4;                   // 1 MiB
  float* up     = (float*)p; p += (size_t)8*8*NN*4;                    // 4 MiB
  float* d2p    = (float*)p; p += (size_t)8*8*4;
  float* dnb    = (float*)p; p += 64;

  k_prep_pack<<<4096, 256, 0, stream>>>(d_A, Apk);
  k_dn<<<BB, 256, 0, stream>>>(d_d, dnb);
  hipMemsetAsync(x, 0, (size_t)BB*NPIX*4, stream);
  hipMemsetAsync(xtt, 0, (size_t)2048*16*8*2, stream);

  for (int it=0; it<9; ++it){
    k_g1c<<<1152, 256, 0, stream>>>(Apk, xtt, x, wK, w1, b1, w2, b2, w3, b3,
                                    alpha, e_part, rk1);
    k_gemm2b<<<1024, 256, 0, stream>>>(Apk, e_part, d_d, up, d2p);
    k_combine3<<<512, 256, 0, stream>>>(up, rk1, d2p, dnb, delta, alpha, beta, x, xtt);
  }

  hipMemcpyAsync(d_out, x, (size_t)BB*NPIX*4, hipMemcpyDeviceToDevice, stream);
}

// Round 15
// 1447.608 us; speedup vs baseline: 1.1604x; 1.1604x over previous
//
#include <hip/hip_runtime.h>
#include <math.h>

#define HH 128
#define NPIX 16384
#define BB 8
#define MM 4096
#define NN 16384
#define LRELU_S 0.1f

typedef __attribute__((ext_vector_type(8))) short bf16x8;
typedef __attribute__((ext_vector_type(4))) float f32x4;

__device__ __forceinline__ float leaky_(float v){ return v >= 0.f ? v : LRELU_S*v; }
__device__ __forceinline__ float clamp01(float v){ return fminf(fmaxf(v, 0.f), 1.f); }
__device__ __forceinline__ float clamp02(float v){ return fminf(fmaxf(v, 0.f), 2.f); }
__device__ __forceinline__ unsigned short f2bf(float f){
  unsigned u = __float_as_uint(f);
  u = (u + 0x7FFFu + ((u >> 16) & 1u)) >> 16;
  return (unsigned short)u;
}
__device__ __forceinline__ float bf2f(unsigned short s){
  return __uint_as_float(((unsigned)s) << 16);
}

// ---------- prep_pack (R13-proven): A f32 -> Apk[((mt*2048+k8)*16+col)*8+e] ----------
__global__ __launch_bounds__(256) void k_prep_pack(const float* __restrict__ A_,
                                                   unsigned short* __restrict__ Apk){
  __shared__ unsigned short lb[16][1032];
  int blk = blockIdx.x;                  // 4096 = mt(256) x ch(16)
  int mt = blk >> 4, ch = blk & 15;
  int t = threadIdx.x;
  #pragma unroll
  for (int i=0;i<16;++i){
    float4 v = *(const float4*)&A_[(size_t)(mt*16+i)*NN + ch*1024 + t*4];
    unsigned short o[4] = {f2bf(v.x),f2bf(v.y),f2bf(v.z),f2bf(v.w)};
    *(uint2*)&lb[i][t*4] = *(uint2*)o;
  }
  __syncthreads();
  size_t base = ((size_t)mt*2048 + ch*128)*128;
  #pragma unroll
  for (int j=0;j<8;++j){
    int o = j*256 + t;
    int k8l = o >> 4, col = o & 15;
    uint4 v = *(const uint4*)&lb[col][k8l*8];
    *(uint4*)&Apk[base + (size_t)o*8] = v;
  }
}

// ---------- prep_atp (R2-proven k_prep, Abf store removed): Atp[(m>>3)*NN + n][8] ----------
__global__ __launch_bounds__(256) void k_prep_atp(const float* __restrict__ A_,
                                                  unsigned short* __restrict__ Atp){
  __shared__ float lds[64][65];
  int bm = blockIdx.x >> 8, bn = blockIdx.x & 255;   // grid 64*256
  int m0 = bm*64, n0 = bn*64;
  int t = threadIdx.x;
  for (int i=t; i<64*16; i+=256){
    int r = i >> 4, c4 = i & 15;
    float4 v = *(const float4*)&A_[(size_t)(m0+r)*NN + n0 + c4*4];
    lds[r][c4*4+0]=v.x; lds[r][c4*4+1]=v.y; lds[r][c4*4+2]=v.z; lds[r][c4*4+3]=v.w;
  }
  __syncthreads();
  for (int i=t; i<8*64; i+=256){
    int mbl = i >> 6, nl = i & 63;
    unsigned short o[8];
    for (int j=0;j<8;++j) o[j] = f2bf(lds[mbl*8+j][nl]);
    *(uint4*)&Atp[((size_t)(m0/8 + mbl)*NN + n0 + nl)*8] = *(uint4*)o;
  }
}

// ---------- dn[b] = ||d[b,:]|| ----------
__global__ __launch_bounds__(256) void k_dn(const float* __restrict__ d, float* __restrict__ dn){
  int b = blockIdx.x, t = threadIdx.x;
  float ss = 0.f;
  for (int m=t; m<MM; m+=256){ float v = d[b*MM + m]; ss += v*v; }
  #pragma unroll
  for (int off=32; off; off>>=1) ss += __shfl_down(ss, off);
  __shared__ float red[4];
  if ((t & 63) == 0) red[t>>6] = ss;
  __syncthreads();
  if (t == 0) dn[b] = sqrtf(red[0]+red[1]+red[2]+red[3]);
}

// ---------- gemm1p (R13-proven verbatim): e_part[4][MM][16] ----------
__global__ __launch_bounds__(256) void k_gemm1p(const unsigned short* __restrict__ Apk,
    const unsigned short* __restrict__ xtt, float* __restrict__ e_part){
  __shared__ float part[4][16][16];
  int blk = blockIdx.x;
  int mt = blk >> 2, ng = blk & 3;
  int t = threadIdx.x, w = t >> 6, lane = t & 63;
  int kg = lane >> 4, col = lane & 15;
  const unsigned short* Ap = Apk + (((size_t)mt*2048 + ng*512 + w*128 + kg)*16 + col)*8;
  const unsigned short* Bp = xtt + ((size_t)(ng*512 + w*128 + kg)*16 + col)*8;
  f32x4 acc = {0.f,0.f,0.f,0.f};
  #pragma unroll 8
  for (int s=0; s<32; ++s){
    bf16x8 a = *(const bf16x8*)(Ap + s*512);
    bf16x8 b = *(const bf16x8*)(Bp + s*512);
    acc = __builtin_amdgcn_mfma_f32_16x16x32_bf16(a, b, acc, 0, 0, 0);
  }
  #pragma unroll
  for (int j=0;j<4;++j) part[w][kg*4+j][col] = acc[j];
  __syncthreads();
  int r = t >> 4, b = t & 15;
  float s = part[0][r][b] + part[1][r][b] + part[2][r][b] + part[3][r][b];
  e_part[((size_t)ng*MM + mt*16 + r)*16 + b] = s;
}

// ---------- conv chain (R4/R13-proven verbatim, 128 blocks x 256 thr) ----------
__global__ __launch_bounds__(256) void k_conv_chain(const float* __restrict__ x,
    const float* __restrict__ wK, const float* __restrict__ w1, const float* __restrict__ b1,
    const float* __restrict__ w2, const float* __restrict__ b2,
    const float* __restrict__ w3, const float* __restrict__ b3,
    const float* __restrict__ alpha, float* __restrict__ rk){
  __shared__ float xs[24][128];
  __shared__ float bufA[2][22][128];
  __shared__ float bufB[2][18][128];
  __shared__ float wKs[18], w1s[100], w2s[100], w3s[100], bs[3][2];
  __shared__ float twoa;
  int blk = blockIdx.x;
  int b = blk >> 4, slab = blk & 15, r0 = slab*8;
  int t = threadIdx.x;
  for (int i=t;i<18;i+=256) wKs[i]=wK[i];
  for (int i=t;i<100;i+=256){ w1s[i]=w1[i]; w2s[i]=w2[i]; w3s[i]=w3[i]; }
  if (t<2){ bs[0][t]=b1[t]; bs[1][t]=b2[t]; bs[2][t]=b3[t]; }
  if (t==0) twoa = 2.f*clamp02(alpha[0]);
  for (int idx=t; idx<24*128; idx+=256){
    int i = idx>>7, j = idx&127, ir = r0-8+i;
    xs[i][j] = ((unsigned)ir < 128u) ? x[b*NPIX + ir*HH + j] : 0.f;
  }
  __syncthreads();
  for (int c=0;c<2;++c)
    for (int idx=t; idx<22*128; idx+=256){
      int i = idx>>7, j = idx&127, ir = r0-7+i;
      float s = 0.f;
      if ((unsigned)ir < 128u){
        #pragma unroll
        for (int di=0;di<3;++di)
          #pragma unroll
          for (int dj=0;dj<3;++dj){
            int jj = j+dj-1;
            if ((unsigned)jj < 128u) s += xs[i+di][jj]*wKs[(c*3+di)*3+dj];
          }
      }
      bufA[c][i][j] = s;
    }
  __syncthreads();
  for (int o=0;o<2;++o)
    for (int idx=t; idx<18*128; idx+=256){
      int i = idx>>7, j = idx&127, ir = r0-5+i;
      float v = 0.f;
      if ((unsigned)ir < 128u){
        float s = bs[0][o];
        #pragma unroll
        for (int c=0;c<2;++c)
          #pragma unroll
          for (int di=0;di<5;++di)
            #pragma unroll
            for (int dj=0;dj<5;++dj){
              int jj = j+dj-2;
              if ((unsigned)jj < 128u) s += bufA[c][i+di][jj]*w1s[(o*2+c)*25+di*5+dj];
            }
        v = bufA[o][i+2][j] + leaky_(s);
      }
      bufB[o][i][j] = v;
    }
  __syncthreads();
  for (int o=0;o<2;++o)
    for (int idx=t; idx<14*128; idx+=256){
      int i = idx>>7, j = idx&127, ir = r0-3+i;
      float v = 0.f;
      if ((unsigned)ir < 128u){
        float s = bs[1][o];
        #pragma unroll
        for (int c=0;c<2;++c)
          #pragma unroll
          for (int di=0;di<5;++di)
            #pragma unroll
            for (int dj=0;dj<5;++dj){
              int jj = j+dj-2;
              if ((unsigned)jj < 128u) s += bufB[c][i+di][jj]*w2s[(o*2+c)*25+di*5+dj];
            }
        v = bufB[o][i+2][j] + leaky_(s);
      }
      bufA[o][i][j] = v;
    }
  __syncthreads();
  for (int o=0;o<2;++o)
    for (int idx=t; idx<10*128; idx+=256){
      int i = idx>>7, j = idx&127, ir = r0-1+i;
      float v = 0.f;
      if ((unsigned)ir < 128u){
        float s = bs[2][o];
        #pragma unroll
        for (int c=0;c<2;++c)
          #pragma unroll
          for (int di=0;di<5;++di)
            #pragma unroll
            for (int dj=0;dj<5;++dj){
              int jj = j+dj-2;
              if ((unsigned)jj < 128u) s += bufA[c][i+di][jj]*w3s[(o*2+c)*25+di*5+dj];
            }
        v = bufA[o][i+2][j] + leaky_(s);
      }
      bufB[o][i][j] = v;
    }
  __syncthreads();
  for (int c=0;c<2;++c)
    for (int idx=t; idx<10*128; idx+=256){
      int i = idx>>7, j = idx&127, ir = r0-1+i;
      float v = 0.f;
      if ((unsigned)ir < 128u){
        float kx = 0.f;
        #pragma unroll
        for (int di=0;di<3;++di)
          #pragma unroll
          for (int dj=0;dj<3;++dj){
            int jj = j+dj-1;
            if ((unsigned)jj < 128u) kx += xs[i+6+di][jj]*wKs[(c*3+di)*3+dj];
          }
        v = twoa*(kx - bufB[c][i][j]);
      }
      bufA[c][i][j] = v;
    }
  __syncthreads();
  for (int idx=t; idx<8*128; idx+=256){
    int i = idx>>7, j = idx&127, ir = r0+i;
    float s = 0.f;
    #pragma unroll
    for (int c=0;c<2;++c)
      #pragma unroll
      for (int di=0;di<3;++di)
        #pragma unroll
        for (int dj=0;dj<3;++dj){
          int jj = j+dj-1;
          if ((unsigned)jj < 128u) s += bufA[c][i+di][jj]*wKs[(c*3+(2-di))*3+(2-dj)];
        }
    rk[b*NPIX + ir*HH + j] = s;
  }
}

// ---------- zt2: e_part reduce -> z, d2p partials, zt pack (no cf). 32 blocks ----------
__global__ __launch_bounds__(256) void k_zt2(const float* __restrict__ e_part,
    const float* __restrict__ d_, unsigned short* __restrict__ zt,
    float* __restrict__ d2p){
  __shared__ float zs[8][128];
  __shared__ float red8s[64];
  int blk = blockIdx.x;                 // 32, m0 = blk*128
  int m0 = blk*128;
  int t = threadIdx.x;
  for (int i=t; i<1024; i+=256){        // R12-proven staging line
    int ml = i >> 3, b = i & 7;
    int m = m0 + ml;
    float s = e_part[(size_t)(0*MM + m)*16 + b]
            + e_part[(size_t)(1*MM + m)*16 + b]
            + e_part[(size_t)(2*MM + m)*16 + b]
            + e_part[(size_t)(3*MM + m)*16 + b];
    zs[b][ml] = s - d_[b*MM + m];
  }
  __syncthreads();
  if (t < 64){                          // R12-proven d2p reduction
    int b = t & 7, g = t >> 3;
    float s = 0.f;
    #pragma unroll
    for (int i=0;i<16;++i){ float v = zs[b][g*16+i]; s += v*v; }
    red8s[g*8 + b] = s;
  }
  __syncthreads();
  if (t < 8){
    float s2 = 0.f;
    #pragma unroll
    for (int g=0;g<8;++g) s2 += red8s[g*8 + t];
    d2p[blk*8 + t] = s2;
  }
  for (int idx=t; idx<128*16; idx+=256){ // R2-proven zt pack form
    int ml = idx >> 4, b = idx & 15, m = m0 + ml;
    float v = (b < 8) ? zs[b][ml] : 0.f;
    zt[(size_t)(m>>3)*128 + b*8 + (m&7)] = f2bf(v);
  }
}

// ---------- g2m (R2-proven k_gemm2mf verbatim): up[2][b16][NN] ----------
__global__ __launch_bounds__(64) void k_g2m(const unsigned short* __restrict__ Atp,
    const unsigned short* __restrict__ zt, float* __restrict__ up){
  int blk = blockIdx.x;               // 2048
  int nt = blk >> 1, ms = blk & 1;
  int lane = threadIdx.x;
  int kg = lane >> 4, nc = lane & 15;
  const unsigned short* Ap = zt  + ((size_t)(ms*256 + kg)*16 + nc)*8;
  const unsigned short* Bp = Atp + ((size_t)(ms*256 + kg)*NN + nt*16 + nc)*8;
  f32x4 acc = {0.f,0.f,0.f,0.f};
  #pragma unroll 8
  for (int s=0; s<64; ++s){
    bf16x8 a = *(const bf16x8*)(Ap + (size_t)s*512);
    bf16x8 b = *(const bf16x8*)(Bp + (size_t)s*4*NN*8);
    acc = __builtin_amdgcn_mfma_f32_16x16x32_bf16(a, b, acc, 0, 0, 0);
  }
  #pragma unroll
  for (int j=0;j<4;++j)
    up[(size_t)(ms*16 + kg*4 + j)*NN + nt*16 + nc] = acc[j];
}

// ---------- combine: cf(d2p,32) + x=clip(x-beta*(rk+cf*(up0+up1))) + xtt pack ----------
__global__ __launch_bounds__(256) void k_combine4(const float* __restrict__ up,
    const float* __restrict__ rk1, const float* __restrict__ d2p,
    const float* __restrict__ dn, const float* __restrict__ delta,
    const float* __restrict__ alpha, const float* __restrict__ beta,
    float* __restrict__ x, unsigned short* __restrict__ xtt){
  __shared__ float cf_s[8];
  int t = threadIdx.x;
  if (t < 8){
    float s2 = 0.f;
    #pragma unroll
    for (int ms=0; ms<32; ++ms) s2 += d2p[ms*8 + t];
    float dist = fmaxf(sqrtf(s2), 1e-10f);
    float de = expf(delta[0]);
    float a = clamp02(alpha[0]);
    cf_s[t] = 2.f*a*(1.f - fminf(1.f, de*dn[t]/dist));
  }
  __syncthreads();
  float bta = clamp02(beta[0]);
  int o = blockIdx.x*256 + t;           // 512 blocks -> 131072 = 8 b x 16384 pix
  int b = o >> 14, pix = o & 16383;
  float s = up[(size_t)(0*16 + b)*NN + pix] + up[(size_t)(1*16 + b)*NN + pix];
  float tot = rk1[b*NPIX + pix] + cf_s[b]*s;
  float xn = clamp01(x[b*NPIX + pix] - bta*tot);
  x[b*NPIX + pix] = xn;
  xtt[((size_t)(pix>>3)*16 + b)*8 + (pix&7)] = f2bf(xn);
}

extern "C" void kernel_launch(void* const* d_in, const int* in_sizes, int n_in,
                              void* d_out, int out_size, void* d_ws, size_t ws_size,
                              hipStream_t stream) {
  const float* d_d   = (const float*)d_in[0];
  const float* d_A   = (const float*)d_in[1];
  const float* w1    = (const float*)d_in[2];
  const float* b1    = (const float*)d_in[3];
  const float* w2    = (const float*)d_in[4];
  const float* b2    = (const float*)d_in[5];
  const float* w3    = (const float*)d_in[6];
  const float* b3    = (const float*)d_in[7];
  const float* wK    = (const float*)d_in[8];
  const float* delta = (const float*)d_in[9];
  const float* alpha = (const float*)d_in[10];
  const float* beta  = (const float*)d_in[12];

  char* p = (char*)d_ws;
  unsigned short* Apk = (unsigned short*)p; p += (size_t)MM*NN*2;      // 128 MiB
  unsigned short* Atp = (unsigned short*)p; p += (size_t)MM*NN*2;      // 128 MiB
  unsigned short* xtt = (unsigned short*)p; p += (size_t)2048*16*8*2;  // 512 KiB
  unsigned short* zt  = (unsigned short*)p; p += (size_t)512*16*8*2;   // 128 KiB
  float* x      = (float*)p; p += (size_t)BB*NPIX*4;
  float* rk1    = (float*)p; p += (size_t)BB*NPIX*4;
  float* e_part = (float*)p; p += (size_t)4*MM*16*4;                   // 1 MiB
  float* up     = (float*)p; p += (size_t)2*16*NN*4;                   // 2 MiB
  float* d2p    = (float*)p; p += (size_t)32*8*4;
  float* dnb    = (float*)p; p += 64;

  k_prep_pack<<<4096, 256, 0, stream>>>(d_A, Apk);
  k_prep_atp<<<64*256, 256, 0, stream>>>(d_A, Atp);
  k_dn<<<BB, 256, 0, stream>>>(d_d, dnb);
  hipMemsetAsync(x, 0, (size_t)BB*NPIX*4, stream);
  hipMemsetAsync(xtt, 0, (size_t)2048*16*8*2, stream);

  for (int it=0; it<9; ++it){
    k_conv_chain<<<128, 256, 0, stream>>>(x, wK, w1, b1, w2, b2, w3, b3, alpha, rk1);
    k_gemm1p<<<1024, 256, 0, stream>>>(Apk, xtt, e_part);
    k_zt2<<<32, 256, 0, stream>>>(e_part, d_d, zt, d2p);
    k_g2m<<<2048, 64, 0, stream>>>(Atp, zt, up);
    k_combine4<<<512, 256, 0, stream>>>(up, rk1, d2p, dnb, delta, alpha, beta, x, xtt);
  }

  hipMemcpyAsync(d_out, x, (size_t)BB*NPIX*4, hipMemcpyDeviceToDevice, stream);
}